// Round 2
// baseline (572.506 us; speedup 1.0000x reference)
//
#include <hip/hip_runtime.h>
#include <math.h>

// Problem constants
#define GS   29
#define GS2  841
#define NCP  24389            // 29^3 control points
#define DW   15
#define PP   225              // DW^2 displacements
#define CH   675              // PP*3 channels per control point
#define CHP  676              // padded row stride (4-elem aligned -> 8B-aligned half4)
#define CC   8                // feature channels
#define VV   64               // volume side
#define V3   262144           // 64^3

typedef __attribute__((ext_vector_type(8))) _Float16 half8;
typedef __attribute__((ext_vector_type(4))) _Float16 half4;

__device__ __forceinline__ float sv(int i) {
    // DR * ((2i+1)/DW - 1)
    return 0.4f * ((2.f * i + 1.f) * (1.f / 15.f) - 1.f);
}

// feat50 (C,D,H,W) fp32 -> two fp16 channel-last volumes:
//   volA: (z,y,x,c)  x fastest   for k=0,1 (lane sweep = x)
//   volB: (z,x,y,c)  y fastest   for k=2   (lane sweep = y)
__global__ __launch_bounds__(256) void make_vols(const float* __restrict__ in,
                                                 _Float16* __restrict__ volA,
                                                 _Float16* __restrict__ volB) {
    int v = blockIdx.x * 256 + threadIdx.x;
    if (v >= V3) return;
    int z = v >> 12, y = (v >> 6) & 63, x = v & 63;
    half8 h;
#pragma unroll
    for (int c = 0; c < CC; c++) h[c] = (_Float16)in[c * V3 + v];
    *(half8*)(volA + (size_t)v * 8) = h;
    *(half8*)(volB + (size_t)((((z << 6) | x) << 6) | y) * 8) = h;
}

// Block per n, 256 threads. Lane p (<225) samples all 3 planes (PAIR fp16 math),
// builds the ORIGINAL-layout (p*3+k) pdd row in LDS, fuses the first
// min3x3->avg3x3 pool, writes both rows contiguously as fp16 (stride CHP).
__global__ __launch_bounds__(256) void pdd_pool_n(const float* __restrict__ f00,
                                                  const _Float16* __restrict__ volA,
                                                  const _Float16* __restrict__ volB,
                                                  const float* __restrict__ grid,
                                                  const float* __restrict__ alpha,
                                                  _Float16* __restrict__ pdd,    // (n, p*3+k) stride CHP
                                                  _Float16* __restrict__ pool) { // (n, p*3+k) stride CHP
    int n = blockIdx.x;
    int tid = threadIdx.x;
    __shared__ __align__(16) _Float16 fixh[8];
    __shared__ float rowp[CH];
    __shared__ float smin[3 * 289];

    float gx = grid[n * 3 + 0], gy = grid[n * 3 + 1], gz = grid[n * 3 + 2];

    if (tid < 8) {
        // trilerp feat00 channel tid at grid point, padding_mode='zeros' (fp32)
        float ix = 0.5f * ((gx + 1.f) * VV - 1.f);
        float iy = 0.5f * ((gy + 1.f) * VV - 1.f);
        float iz = 0.5f * ((gz + 1.f) * VV - 1.f);
        float x0f = floorf(ix), y0f = floorf(iy), z0f = floorf(iz);
        float fx = ix - x0f, fy = iy - y0f, fz = iz - z0f;
        int x0 = (int)x0f, y0 = (int)y0f, z0 = (int)z0f;
        const float* fc = f00 + tid * V3;
        float acc = 0.f;
        for (int dz = 0; dz < 2; dz++) {
            int zi = z0 + dz; float wz = dz ? fz : 1.f - fz;
            for (int dy = 0; dy < 2; dy++) {
                int yi = y0 + dy; float wy = dy ? fy : 1.f - fy;
                for (int dx = 0; dx < 2; dx++) {
                    int xi = x0 + dx; float wx = dx ? fx : 1.f - fx;
                    if (xi >= 0 && xi < VV && yi >= 0 && yi < VV && zi >= 0 && zi < VV)
                        acc += wx * wy * wz * fc[(zi * VV + yi) * VV + xi];
                }
            }
        }
        fixh[tid] = (_Float16)acc;
    }
    __syncthreads();

    if (tid < PP) {
        int p = tid;
        int h_ = p / 15, w_ = p - 15 * h_;
        float A = sv(h_), B = sv(w_);
        half8 f8 = *(const half8*)fixh;
        float a0 = alpha[0], a1 = alpha[1];

        for (int k = 0; k < 3; k++) {
            float pu, pv, pw;
            const _Float16* vol;
            if (k == 0)      { pu = gx + B; pv = gy + A; pw = gz;     vol = volA; }
            else if (k == 1) { pu = gx + B; pv = gy;     pw = gz + A; vol = volA; }
            else             { pu = gy + B; pv = gx;     pw = gz + A; vol = volB; }

            float iu = 0.5f * ((pu + 1.f) * VV - 1.f);
            float iv = 0.5f * ((pv + 1.f) * VV - 1.f);
            float iw = 0.5f * ((pw + 1.f) * VV - 1.f);
            float u0f = floorf(iu), v0f = floorf(iv), w0f = floorf(iw);
            float fu = iu - u0f, fv = iv - v0f, fw = iw - w0f;
            int u0 = (int)u0f, v0 = (int)v0f, w0 = (int)w0f;

            // u as adjacent voxel PAIR: one 32B load pair gets both u-corners
            int p0 = min(max(u0, 0), VV - 2);
            float wAu = (u0 < 0) ? 1.f : ((u0 >= VV - 1) ? 0.f : (1.f - fu));
            float wBu = 1.f - wAu;
            int v0c = min(max(v0, 0), VV - 1), v1c = min(max(v0 + 1, 0), VV - 1);
            int w0c = min(max(w0, 0), VV - 1), w1c = min(max(w0 + 1, 0), VV - 1);
            float wv0 = 1.f - fv, wv1 = fv;
            float ww0 = 1.f - fw, ww1 = fw;

            half8 acc = {0, 0, 0, 0, 0, 0, 0, 0};
#define PAIR(WC, VC, WGT) {                                               \
                float fA_ = (WGT) * wAu, fB_ = (WGT) * wBu;               \
                _Float16 hA_ = (_Float16)fA_, hB_ = (_Float16)fB_;        \
                half8 hA8 = {hA_, hA_, hA_, hA_, hA_, hA_, hA_, hA_};     \
                half8 hB8 = {hB_, hB_, hB_, hB_, hB_, hB_, hB_, hB_};     \
                const _Float16* vp = vol + (size_t)((((WC) * VV) + (VC)) * VV + p0) * 8; \
                half8 lo = *(const half8*)vp;                             \
                half8 hi = *(const half8*)(vp + 8);                       \
                acc += hA8 * lo;                                          \
                acc += hB8 * hi;                                          \
            }
            PAIR(w0c, v0c, ww0 * wv0)
            PAIR(w0c, v1c, ww0 * wv1)
            PAIR(w1c, v0c, ww1 * wv0)
            PAIR(w1c, v1c, ww1 * wv1)
#undef PAIR

            half8 d8 = f8 - acc;
            float ssd = 0.f;
#pragma unroll
            for (int c = 0; c < 8; c++) { float dc = (float)d8[c]; ssd = fmaf(dc, dc, ssd); }
            rowp[p * 3 + k] = a1 + a0 * ssd;
        }
    }
    __syncthreads();

    // min3x3 over pad-2 edge-clamped 15x15, per k: 3*17*17 = 867 outputs
    for (int idx = tid; idx < 867; idx += 256) {
        int k = idx / 289; int r = idx - 289 * k; int a = r / 17; int b = r - 17 * a;
        float mn = 1e30f;
        for (int u = 0; u < 3; u++) {
            int hh = min(max(a + u - 2, 0), 14);
            for (int v = 0; v < 3; v++) {
                int ww = min(max(b + v - 2, 0), 14);
                mn = fminf(mn, rowp[(hh * 15 + ww) * 3 + k]);
            }
        }
        smin[idx] = mn;
    }
    __syncthreads();

    for (int i = tid; i < CH; i += 256) {
        pdd[(size_t)n * CHP + i] = (_Float16)rowp[i];
        int p = i / 3, k = i - 3 * p;              // i = p*3+k
        int h = p / 15, w = p - 15 * h;
        float acc = 0.f;
        for (int a = 0; a < 3; a++)
            for (int b = 0; b < 3; b++)
                acc += smin[k * 289 + (h + a) * 17 + (w + b)];
        pool[(size_t)n * CHP + i] = (_Float16)(acc * (1.f / 9.f));
    }
}

// Fused: S1 = grid_smooth(pool1) as direct 25-tap gather (== two clamped 1-D
// 5-tap triangle passes), cost = a4 + a2*pdd + a3*S1 (fp32, in LDS),
// then min3x3(pad2)+avg3x3 -> pool2 (fp16, stride CHP).
__global__ __launch_bounds__(256) void cost_pool2(const _Float16* __restrict__ pool1,
                                                  const _Float16* __restrict__ pdd,
                                                  const float* __restrict__ alpha,
                                                  _Float16* __restrict__ pool2) {
    int n = blockIdx.x, tid = threadIdx.x;
    int x = n % GS; int zy = n / GS; int y = zy % GS; int z = zy / GS;
    __shared__ int   sbase[25];
    __shared__ float swt[25];
    __shared__ float rowp[CHP];          // fp32 cost row; slot 675 = pad (unused)
    __shared__ float smn[17 * 17 * 3];

    if (tid < 25) {
        int dz = tid / 5, dy = tid - 5 * (tid / 5);
        int zz = min(max(z + dz - 2, 0), GS - 1);
        int yy = min(max(y + dy - 2, 0), GS - 1);
        sbase[tid] = ((zz * GS + yy) * GS + x) * CHP;
        float tz = 3.f - fabsf((float)dz - 2.f);   // {1,2,3,2,1}
        float ty = 3.f - fabsf((float)dy - 2.f);
        swt[tid] = tz * ty * (1.f / 81.f);
    }
    __syncthreads();

    if (tid < 169) {                     // 169*4 = 676 channels (incl. pad)
        int c0 = tid * 4;
        float s0 = 0.f, s1 = 0.f, s2 = 0.f, s3 = 0.f;
#pragma unroll
        for (int t = 0; t < 25; t++) {
            int off = sbase[t] + c0;
            float w = swt[t];
            half4 hv = *(const half4*)(pool1 + off);   // 8B aligned: CHP%4==0
            s0 = fmaf(w, (float)hv[0], s0);
            s1 = fmaf(w, (float)hv[1], s1);
            s2 = fmaf(w, (float)hv[2], s2);
            s3 = fmaf(w, (float)hv[3], s3);
        }
        float a2 = alpha[2], a3 = alpha[3], a4 = alpha[4];
        half4 pv = *(const half4*)(pdd + (size_t)n * CHP + c0);
        rowp[c0 + 0] = a4 + a2 * (float)pv[0] + a3 * s0;
        rowp[c0 + 1] = a4 + a2 * (float)pv[1] + a3 * s1;
        rowp[c0 + 2] = a4 + a2 * (float)pv[2] + a3 * s2;
        rowp[c0 + 3] = a4 + a2 * (float)pv[3] + a3 * s3;
    }
    __syncthreads();

    // min3x3 over pad-2 edge-clamped 15x15, per k: 3*17*17 = 867 outputs
    for (int idx = tid; idx < 867; idx += 256) {
        int k = idx / 289; int r = idx - 289 * k; int a = r / 17; int b = r - 17 * a;
        float mn = 1e30f;
        for (int u = 0; u < 3; u++) {
            int hh = min(max(a + u - 2, 0), 14);
            for (int v = 0; v < 3; v++) {
                int ww = min(max(b + v - 2, 0), 14);
                mn = fminf(mn, rowp[(hh * 15 + ww) * 3 + k]);
            }
        }
        smn[idx] = mn;
    }
    __syncthreads();

    for (int i = tid; i < CH; i += 256) {
        int p = i / 3, k = i - 3 * p;
        int h = p / 15, w = p - 15 * h;
        float acc = 0.f;
        for (int a = 0; a < 3; a++)
            for (int b = 0; b < 3; b++)
                acc += smn[k * 289 + (h + a) * 17 + (w + b)];
        pool2[(size_t)n * CHP + i] = (_Float16)(acc * (1.f / 9.f));
    }
}

// Fused: cost_avg = grid_smooth(pool2) as 25-tap gather (fp32, write out2),
// then softmax over p per (n,k) + pred_xyz einsum, straight from LDS.
__global__ __launch_bounds__(256) void smooth_softmax(const _Float16* __restrict__ pool2,
                                                      const float* __restrict__ alpha,
                                                      float* __restrict__ ca,     // cost_avg (N*675 fp32)
                                                      float* __restrict__ soft,   // cost_soft (N*675 fp32)
                                                      float* __restrict__ pred) { // pred_xyz (N*3)
    int n = blockIdx.x, tid = threadIdx.x;
    int x = n % GS; int zy = n / GS; int y = zy % GS; int z = zy / GS;
    int wave = tid >> 6, lane = tid & 63;
    __shared__ int   sbase[25];
    __shared__ float swt[25];
    __shared__ float vals[CHP];          // fp32 cost_avg row; slot 675 = pad
    __shared__ float partial[3][3];

    if (tid < 25) {
        int dz = tid / 5, dy = tid - 5 * (tid / 5);
        int zz = min(max(z + dz - 2, 0), GS - 1);
        int yy = min(max(y + dy - 2, 0), GS - 1);
        sbase[tid] = ((zz * GS + yy) * GS + x) * CHP;
        float tz = 3.f - fabsf((float)dz - 2.f);
        float ty = 3.f - fabsf((float)dy - 2.f);
        swt[tid] = tz * ty * (1.f / 81.f);
    }
    __syncthreads();

    if (tid < 169) {
        int c0 = tid * 4;
        float s0 = 0.f, s1 = 0.f, s2 = 0.f, s3 = 0.f;
#pragma unroll
        for (int t = 0; t < 25; t++) {
            int off = sbase[t] + c0;
            float w = swt[t];
            half4 hv = *(const half4*)(pool2 + off);
            s0 = fmaf(w, (float)hv[0], s0);
            s1 = fmaf(w, (float)hv[1], s1);
            s2 = fmaf(w, (float)hv[2], s2);
            s3 = fmaf(w, (float)hv[3], s3);
        }
        vals[c0 + 0] = s0;
        vals[c0 + 1] = s1;
        vals[c0 + 2] = s2;
        vals[c0 + 3] = s3;
    }
    __syncthreads();

    // write cost_avg (fp32, exact 675 stride)
    for (int i = tid; i < CH; i += 256) ca[(size_t)n * CH + i] = vals[i];
    __syncthreads();

    float a5 = alpha[5];
    if (wave < 3) {
        int k = wave;
        float v[4], e[4];
        float m = -1e30f;
#pragma unroll
        for (int j = 0; j < 4; j++) {
            int p = lane + 64 * j;
            v[j] = (p < PP) ? -a5 * vals[p * 3 + k] : -1e30f;
            m = fmaxf(m, v[j]);
        }
#pragma unroll
        for (int o = 32; o > 0; o >>= 1) m = fmaxf(m, __shfl_xor(m, o));
        float sum = 0.f;
#pragma unroll
        for (int j = 0; j < 4; j++) {
            int p = lane + 64 * j;
            e[j] = (p < PP) ? __expf(v[j] - m) : 0.f;
            sum += e[j];
        }
#pragma unroll
        for (int o = 32; o > 0; o >>= 1) sum += __shfl_xor(sum, o);
        float inv = 1.f / sum;
        float px = 0.f, py = 0.f, pz = 0.f;
#pragma unroll
        for (int j = 0; j < 4; j++) {
            int p = lane + 64 * j;
            if (p < PP) {
                float s = e[j] * inv;
                vals[p * 3 + k] = s;
                int h_ = p / 15, w_ = p - 15 * h_;
                float A = sv(h_), B = sv(w_);
                if (k == 0)      { px += s * B; py += s * A; }
                else if (k == 1) { px += s * B; pz += s * A; }
                else             { py += s * B; pz += s * A; }
            }
        }
#pragma unroll
        for (int o = 32; o > 0; o >>= 1) {
            px += __shfl_xor(px, o);
            py += __shfl_xor(py, o);
            pz += __shfl_xor(pz, o);
        }
        if (lane == 0) { partial[k][0] = px; partial[k][1] = py; partial[k][2] = pz; }
    }
    __syncthreads();
    if (tid < 3) pred[(size_t)n * 3 + tid] = 0.5f * (partial[0][tid] + partial[1][tid] + partial[2][tid]);
    for (int i = tid; i < CH; i += 256) soft[(size_t)n * CH + i] = vals[i];
}

extern "C" void kernel_launch(void* const* d_in, const int* in_sizes, int n_in,
                              void* d_out, int out_size, void* d_ws, size_t ws_size,
                              hipStream_t stream) {
    const float* f00   = (const float*)d_in[0];
    const float* f50   = (const float*)d_in[1];
    // d_in[2] (shift_2d_min) broadcast of shift_2d -- unused
    const float* grid  = (const float*)d_in[3];
    // d_in[4] (shift_2d) recomputed analytically -- unused
    const float* alpha = (const float*)d_in[5];

    float* out0 = (float*)d_out;                   // cost_soft  (N*675)
    float* out1 = out0 + (size_t)NCP * CH;         // pred_xyz   (N*3)
    float* out2 = out1 + (size_t)NCP * 3;          // cost_avg   (N*675)

    char* ws = (char*)d_ws;
    _Float16* volA = (_Float16*)ws;                          // 4MB
    _Float16* volB = volA + (size_t)V3 * 8;                  // 4MB
    _Float16* H0 = volB + (size_t)V3 * 8;                    // N*CHP fp16 (pdd)
    _Float16* H1 = H0 + (size_t)NCP * CHP;                   // N*CHP fp16 (pool1)
    _Float16* H2 = H1 + (size_t)NCP * CHP;                   // N*CHP fp16 (pool2)

    make_vols<<<(V3 + 255) / 256, 256, 0, stream>>>(f50, volA, volB);

    // pdd + pool1 fused, ORIGINAL (p*3+k) layout rows, contiguous fp16 writes
    pdd_pool_n<<<NCP, 256, 0, stream>>>(f00, volA, volB, grid, alpha, H0, H1);

    // cost = a4 + a2*pdd + a3*smooth(pool1); min+avg pool -> pool2
    cost_pool2<<<NCP, 256, 0, stream>>>(H1, H0, alpha, H2);

    // cost_avg = smooth(pool2) -> out2; softmax + pred -> out0, out1
    smooth_softmax<<<NCP, 256, 0, stream>>>(H2, alpha, out2, out0, out1);
}

// Round 3
// 534.230 us; speedup vs baseline: 1.0716x; 1.0716x over previous
//
#include <hip/hip_runtime.h>
#include <math.h>

// Problem constants
#define GS   29
#define GS2  841
#define NCP  24389            // 29^3 control points
#define DW   15
#define PP   225              // DW^2 displacements
#define CH   675              // PP*3 channels per control point
#define CHP  676              // padded row stride (4-elem aligned -> 8B-aligned half4)
#define CC   8                // feature channels
#define VV   64               // volume side
#define V3   262144           // 64^3

typedef __attribute__((ext_vector_type(8))) _Float16 half8;
typedef __attribute__((ext_vector_type(4))) _Float16 half4;

__device__ __forceinline__ float sv(int i) {
    // DR * ((2i+1)/DW - 1)
    return 0.4f * ((2.f * i + 1.f) * (1.f / 15.f) - 1.f);
}

// feat50 (C,D,H,W) fp32 -> two fp16 channel-last volumes:
//   volA: (z,y,x,c)  x fastest   for k=0,1 (lane sweep = x)
//   volB: (z,x,y,c)  y fastest   for k=2   (lane sweep = y)
__global__ __launch_bounds__(256) void make_vols(const float* __restrict__ in,
                                                 _Float16* __restrict__ volA,
                                                 _Float16* __restrict__ volB) {
    int v = blockIdx.x * 256 + threadIdx.x;
    if (v >= V3) return;
    int z = v >> 12, y = (v >> 6) & 63, x = v & 63;
    half8 h;
#pragma unroll
    for (int c = 0; c < CC; c++) h[c] = (_Float16)in[c * V3 + v];
    *(half8*)(volA + (size_t)v * 8) = h;
    *(half8*)(volB + (size_t)((((z << 6) | x) << 6) | y) * 8) = h;
}

// Block per n, 256 threads. Lane p (<225) samples all 3 planes (PAIR fp16 math),
// builds the ORIGINAL-layout (p*3+k) pdd row in LDS, fuses the first
// min3x3->avg3x3 pool, writes both rows contiguously as fp16 (stride CHP).
__global__ __launch_bounds__(256) void pdd_pool_n(const float* __restrict__ f00,
                                                  const _Float16* __restrict__ volA,
                                                  const _Float16* __restrict__ volB,
                                                  const float* __restrict__ grid,
                                                  const float* __restrict__ alpha,
                                                  _Float16* __restrict__ pdd,    // (n, p*3+k) stride CHP
                                                  _Float16* __restrict__ pool) { // (n, p*3+k) stride CHP
    int n = blockIdx.x;
    int tid = threadIdx.x;
    __shared__ __align__(16) _Float16 fixh[8];
    __shared__ float rowp[CH];
    __shared__ float smin[3 * 289];

    float gx = grid[n * 3 + 0], gy = grid[n * 3 + 1], gz = grid[n * 3 + 2];

    if (tid < 8) {
        // trilerp feat00 channel tid at grid point, padding_mode='zeros' (fp32)
        float ix = 0.5f * ((gx + 1.f) * VV - 1.f);
        float iy = 0.5f * ((gy + 1.f) * VV - 1.f);
        float iz = 0.5f * ((gz + 1.f) * VV - 1.f);
        float x0f = floorf(ix), y0f = floorf(iy), z0f = floorf(iz);
        float fx = ix - x0f, fy = iy - y0f, fz = iz - z0f;
        int x0 = (int)x0f, y0 = (int)y0f, z0 = (int)z0f;
        const float* fc = f00 + tid * V3;
        float acc = 0.f;
        for (int dz = 0; dz < 2; dz++) {
            int zi = z0 + dz; float wz = dz ? fz : 1.f - fz;
            for (int dy = 0; dy < 2; dy++) {
                int yi = y0 + dy; float wy = dy ? fy : 1.f - fy;
                for (int dx = 0; dx < 2; dx++) {
                    int xi = x0 + dx; float wx = dx ? fx : 1.f - fx;
                    if (xi >= 0 && xi < VV && yi >= 0 && yi < VV && zi >= 0 && zi < VV)
                        acc += wx * wy * wz * fc[(zi * VV + yi) * VV + xi];
                }
            }
        }
        fixh[tid] = (_Float16)acc;
    }
    __syncthreads();

    if (tid < PP) {
        int p = tid;
        int h_ = p / 15, w_ = p - 15 * h_;
        float A = sv(h_), B = sv(w_);
        half8 f8 = *(const half8*)fixh;
        float a0 = alpha[0], a1 = alpha[1];

        for (int k = 0; k < 3; k++) {
            float pu, pv, pw;
            const _Float16* vol;
            if (k == 0)      { pu = gx + B; pv = gy + A; pw = gz;     vol = volA; }
            else if (k == 1) { pu = gx + B; pv = gy;     pw = gz + A; vol = volA; }
            else             { pu = gy + B; pv = gx;     pw = gz + A; vol = volB; }

            float iu = 0.5f * ((pu + 1.f) * VV - 1.f);
            float iv = 0.5f * ((pv + 1.f) * VV - 1.f);
            float iw = 0.5f * ((pw + 1.f) * VV - 1.f);
            float u0f = floorf(iu), v0f = floorf(iv), w0f = floorf(iw);
            float fu = iu - u0f, fv = iv - v0f, fw = iw - w0f;
            int u0 = (int)u0f, v0 = (int)v0f, w0 = (int)w0f;

            // u as adjacent voxel PAIR: one 32B load pair gets both u-corners
            int p0 = min(max(u0, 0), VV - 2);
            float wAu = (u0 < 0) ? 1.f : ((u0 >= VV - 1) ? 0.f : (1.f - fu));
            float wBu = 1.f - wAu;
            int v0c = min(max(v0, 0), VV - 1), v1c = min(max(v0 + 1, 0), VV - 1);
            int w0c = min(max(w0, 0), VV - 1), w1c = min(max(w0 + 1, 0), VV - 1);
            float wv0 = 1.f - fv, wv1 = fv;
            float ww0 = 1.f - fw, ww1 = fw;

            half8 acc = {0, 0, 0, 0, 0, 0, 0, 0};
#define PAIR(WC, VC, WGT) {                                               \
                float fA_ = (WGT) * wAu, fB_ = (WGT) * wBu;               \
                _Float16 hA_ = (_Float16)fA_, hB_ = (_Float16)fB_;        \
                half8 hA8 = {hA_, hA_, hA_, hA_, hA_, hA_, hA_, hA_};     \
                half8 hB8 = {hB_, hB_, hB_, hB_, hB_, hB_, hB_, hB_};     \
                const _Float16* vp = vol + (size_t)((((WC) * VV) + (VC)) * VV + p0) * 8; \
                half8 lo = *(const half8*)vp;                             \
                half8 hi = *(const half8*)(vp + 8);                       \
                acc += hA8 * lo;                                          \
                acc += hB8 * hi;                                          \
            }
            PAIR(w0c, v0c, ww0 * wv0)
            PAIR(w0c, v1c, ww0 * wv1)
            PAIR(w1c, v0c, ww1 * wv0)
            PAIR(w1c, v1c, ww1 * wv1)
#undef PAIR

            half8 d8 = f8 - acc;
            float ssd = 0.f;
#pragma unroll
            for (int c = 0; c < 8; c++) { float dc = (float)d8[c]; ssd = fmaf(dc, dc, ssd); }
            rowp[p * 3 + k] = a1 + a0 * ssd;
        }
    }
    __syncthreads();

    // min3x3 over pad-2 edge-clamped 15x15, per k: 3*17*17 = 867 outputs
    for (int idx = tid; idx < 867; idx += 256) {
        int k = idx / 289; int r = idx - 289 * k; int a = r / 17; int b = r - 17 * a;
        float mn = 1e30f;
        for (int u = 0; u < 3; u++) {
            int hh = min(max(a + u - 2, 0), 14);
            for (int v = 0; v < 3; v++) {
                int ww = min(max(b + v - 2, 0), 14);
                mn = fminf(mn, rowp[(hh * 15 + ww) * 3 + k]);
            }
        }
        smin[idx] = mn;
    }
    __syncthreads();

    for (int i = tid; i < CH; i += 256) {
        pdd[(size_t)n * CHP + i] = (_Float16)rowp[i];
        int p = i / 3, k = i - 3 * p;              // i = p*3+k
        int h = p / 15, w = p - 15 * h;
        float acc = 0.f;
        for (int a = 0; a < 3; a++)
            for (int b = 0; b < 3; b++)
                acc += smin[k * 289 + (h + a) * 17 + (w + b)];
        pool[(size_t)n * CHP + i] = (_Float16)(acc * (1.f / 9.f));
    }
}

// z-axis 5-tap triangle [1,2,3,2,1]/9, edge-clamped, sliding window.
// One thread per (row=z*GS2-slice position... actually per (zy-row, half4 chunk)):
// column along z at fixed (y,x,c0..c0+3). half4 loads: 8B/lane, coalesced.
__global__ __launch_bounds__(256) void gs_z4(const _Float16* __restrict__ in,
                                             _Float16* __restrict__ out) {
    const int COLS = GS2 * 169;            // (y,x) rows x 169 half4 chunks
    int id = blockIdx.x * 256 + threadIdx.x;
    if (id >= COLS) return;
    int row = id / 169, c4 = id - 169 * row;
    size_t base = (size_t)row * CHP + c4 * 4;
    const size_t ZS = (size_t)GS2 * CHP;
    const float w0 = 1.f / 9.f, w1 = 2.f / 9.f, w2 = 3.f / 9.f;

    half4 h0 = *(const half4*)(in + base);
    half4 h3 = *(const half4*)(in + base + ZS);
    half4 h4 = *(const half4*)(in + base + 2 * ZS);
    float v0[4], v1[4], v2[4], v3[4], v4[4];
#pragma unroll
    for (int j = 0; j < 4; j++) {
        v0[j] = (float)h0[j]; v1[j] = v0[j]; v2[j] = v0[j];
        v3[j] = (float)h3[j]; v4[j] = (float)h4[j];
    }
    for (int z = 0; z < GS; z++) {
        half4 o;
#pragma unroll
        for (int j = 0; j < 4; j++)
            o[j] = (_Float16)(w0 * (v0[j] + v4[j]) + w1 * (v1[j] + v3[j]) + w2 * v2[j]);
        *(half4*)(out + base + (size_t)z * ZS) = o;
        int zn = z + 3; if (zn > GS - 1) zn = GS - 1;
        half4 hn = *(const half4*)(in + base + (size_t)zn * ZS);
#pragma unroll
        for (int j = 0; j < 4; j++) {
            v0[j] = v1[j]; v1[j] = v2[j]; v2[j] = v3[j]; v3[j] = v4[j];
            v4[j] = (float)hn[j];
        }
    }
}

// Per n: y-axis 5-tap triangle on z-smoothed pool1 (5-row gather),
// cost = a4 + a2*pdd + a3*smooth (fp32 in LDS), min3x3+avg3x3 -> pool2.
__global__ __launch_bounds__(256) void cost_pool2_y(const _Float16* __restrict__ zs,
                                                    const _Float16* __restrict__ pdd,
                                                    const float* __restrict__ alpha,
                                                    _Float16* __restrict__ pool2) {
    int n = blockIdx.x, tid = threadIdx.x;
    int x = n % GS; int zy = n / GS; int y = zy % GS; int z = zy / GS;
    __shared__ float rowp[CHP];
    __shared__ float smn[17 * 17 * 3];

    if (tid < 169) {
        int c0 = tid * 4;
        float s0 = 0.f, s1 = 0.f, s2 = 0.f, s3 = 0.f;
#pragma unroll
        for (int dy = 0; dy < 5; dy++) {
            int yy = min(max(y + dy - 2, 0), GS - 1);
            size_t off = ((size_t)(z * GS + yy) * GS + x) * CHP + c0;
            float w = (3.f - fabsf((float)dy - 2.f)) * (1.f / 9.f);
            half4 hv = *(const half4*)(zs + off);
            s0 = fmaf(w, (float)hv[0], s0);
            s1 = fmaf(w, (float)hv[1], s1);
            s2 = fmaf(w, (float)hv[2], s2);
            s3 = fmaf(w, (float)hv[3], s3);
        }
        float a2 = alpha[2], a3 = alpha[3], a4 = alpha[4];
        half4 pv = *(const half4*)(pdd + (size_t)n * CHP + c0);
        rowp[c0 + 0] = a4 + a2 * (float)pv[0] + a3 * s0;
        rowp[c0 + 1] = a4 + a2 * (float)pv[1] + a3 * s1;
        rowp[c0 + 2] = a4 + a2 * (float)pv[2] + a3 * s2;
        rowp[c0 + 3] = a4 + a2 * (float)pv[3] + a3 * s3;
    }
    __syncthreads();

    // min3x3 over pad-2 edge-clamped 15x15, per k: 3*17*17 = 867 outputs
    for (int idx = tid; idx < 867; idx += 256) {
        int k = idx / 289; int r = idx - 289 * k; int a = r / 17; int b = r - 17 * a;
        float mn = 1e30f;
        for (int u = 0; u < 3; u++) {
            int hh = min(max(a + u - 2, 0), 14);
            for (int v = 0; v < 3; v++) {
                int ww = min(max(b + v - 2, 0), 14);
                mn = fminf(mn, rowp[(hh * 15 + ww) * 3 + k]);
            }
        }
        smn[idx] = mn;
    }
    __syncthreads();

    for (int i = tid; i < CH; i += 256) {
        int p = i / 3, k = i - 3 * p;
        int h = p / 15, w = p - 15 * h;
        float acc = 0.f;
        for (int a = 0; a < 3; a++)
            for (int b = 0; b < 3; b++)
                acc += smn[k * 289 + (h + a) * 17 + (w + b)];
        pool2[(size_t)n * CHP + i] = (_Float16)(acc * (1.f / 9.f));
    }
}

// Per n: y-axis 5-tap triangle on z-smoothed pool2 -> cost_avg (fp32, out2),
// then softmax over p per (n,k) + pred_xyz einsum straight from LDS.
__global__ __launch_bounds__(256) void smooth_y_softmax(const _Float16* __restrict__ zs,
                                                        const float* __restrict__ alpha,
                                                        float* __restrict__ ca,     // cost_avg (N*675 fp32)
                                                        float* __restrict__ soft,   // cost_soft (N*675 fp32)
                                                        float* __restrict__ pred) { // pred_xyz (N*3)
    int n = blockIdx.x, tid = threadIdx.x;
    int x = n % GS; int zy = n / GS; int y = zy % GS; int z = zy / GS;
    int wave = tid >> 6, lane = tid & 63;
    __shared__ float vals[CHP];
    __shared__ float partial[3][3];

    if (tid < 169) {
        int c0 = tid * 4;
        float s0 = 0.f, s1 = 0.f, s2 = 0.f, s3 = 0.f;
#pragma unroll
        for (int dy = 0; dy < 5; dy++) {
            int yy = min(max(y + dy - 2, 0), GS - 1);
            size_t off = ((size_t)(z * GS + yy) * GS + x) * CHP + c0;
            float w = (3.f - fabsf((float)dy - 2.f)) * (1.f / 9.f);
            half4 hv = *(const half4*)(zs + off);
            s0 = fmaf(w, (float)hv[0], s0);
            s1 = fmaf(w, (float)hv[1], s1);
            s2 = fmaf(w, (float)hv[2], s2);
            s3 = fmaf(w, (float)hv[3], s3);
        }
        vals[c0 + 0] = s0;
        vals[c0 + 1] = s1;
        vals[c0 + 2] = s2;
        vals[c0 + 3] = s3;
    }
    __syncthreads();

    // write cost_avg (fp32, exact 675 stride)
    for (int i = tid; i < CH; i += 256) ca[(size_t)n * CH + i] = vals[i];
    __syncthreads();

    float a5 = alpha[5];
    if (wave < 3) {
        int k = wave;
        float v[4], e[4];
        float m = -1e30f;
#pragma unroll
        for (int j = 0; j < 4; j++) {
            int p = lane + 64 * j;
            v[j] = (p < PP) ? -a5 * vals[p * 3 + k] : -1e30f;
            m = fmaxf(m, v[j]);
        }
#pragma unroll
        for (int o = 32; o > 0; o >>= 1) m = fmaxf(m, __shfl_xor(m, o));
        float sum = 0.f;
#pragma unroll
        for (int j = 0; j < 4; j++) {
            int p = lane + 64 * j;
            e[j] = (p < PP) ? __expf(v[j] - m) : 0.f;
            sum += e[j];
        }
#pragma unroll
        for (int o = 32; o > 0; o >>= 1) sum += __shfl_xor(sum, o);
        float inv = 1.f / sum;
        float px = 0.f, py = 0.f, pz = 0.f;
#pragma unroll
        for (int j = 0; j < 4; j++) {
            int p = lane + 64 * j;
            if (p < PP) {
                float s = e[j] * inv;
                vals[p * 3 + k] = s;
                int h_ = p / 15, w_ = p - 15 * h_;
                float A = sv(h_), B = sv(w_);
                if (k == 0)      { px += s * B; py += s * A; }
                else if (k == 1) { px += s * B; pz += s * A; }
                else             { py += s * B; pz += s * A; }
            }
        }
#pragma unroll
        for (int o = 32; o > 0; o >>= 1) {
            px += __shfl_xor(px, o);
            py += __shfl_xor(py, o);
            pz += __shfl_xor(pz, o);
        }
        if (lane == 0) { partial[k][0] = px; partial[k][1] = py; partial[k][2] = pz; }
    }
    __syncthreads();
    if (tid < 3) pred[(size_t)n * 3 + tid] = 0.5f * (partial[0][tid] + partial[1][tid] + partial[2][tid]);
    for (int i = tid; i < CH; i += 256) soft[(size_t)n * CH + i] = vals[i];
}

extern "C" void kernel_launch(void* const* d_in, const int* in_sizes, int n_in,
                              void* d_out, int out_size, void* d_ws, size_t ws_size,
                              hipStream_t stream) {
    const float* f00   = (const float*)d_in[0];
    const float* f50   = (const float*)d_in[1];
    // d_in[2] (shift_2d_min) broadcast of shift_2d -- unused
    const float* grid  = (const float*)d_in[3];
    // d_in[4] (shift_2d) recomputed analytically -- unused
    const float* alpha = (const float*)d_in[5];

    float* out0 = (float*)d_out;                   // cost_soft  (N*675)
    float* out1 = out0 + (size_t)NCP * CH;         // pred_xyz   (N*3)
    float* out2 = out1 + (size_t)NCP * 3;          // cost_avg   (N*675)

    char* ws = (char*)d_ws;
    _Float16* volA = (_Float16*)ws;                          // 4MB
    _Float16* volB = volA + (size_t)V3 * 8;                  // 4MB
    _Float16* H0 = volB + (size_t)V3 * 8;                    // N*CHP fp16 (pdd)
    _Float16* H1 = H0 + (size_t)NCP * CHP;                   // N*CHP fp16 (pool1 -> pool2)
    _Float16* H2 = H1 + (size_t)NCP * CHP;                   // N*CHP fp16 (z-smooth tmp)

    make_vols<<<(V3 + 255) / 256, 256, 0, stream>>>(f50, volA, volB);

    // pdd + pool1 fused, ORIGINAL (p*3+k) layout rows, contiguous fp16 writes
    pdd_pool_n<<<NCP, 256, 0, stream>>>(f00, volA, volB, grid, alpha, H0, H1);

    const int COLS = GS2 * 169;
    const int gbz = (COLS + 255) / 256;

    // smooth1 = z-pass (streaming) + y-pass fused into cost+pool2 (5-row gather)
    gs_z4<<<gbz, 256, 0, stream>>>(H1, H2);
    cost_pool2_y<<<NCP, 256, 0, stream>>>(H2, H0, alpha, H1);   // pool2 -> H1

    // smooth2 = z-pass + y-pass fused into cost_avg + softmax
    gs_z4<<<gbz, 256, 0, stream>>>(H1, H2);
    smooth_y_softmax<<<NCP, 256, 0, stream>>>(H2, alpha, out2, out0, out1);
}

// Round 5
// 485.137 us; speedup vs baseline: 1.1801x; 1.1012x over previous
//
#include <hip/hip_runtime.h>
#include <math.h>

// Problem constants
#define GS   29
#define GS2  841
#define NCP  24389            // 29^3 control points
#define DW   15
#define PP   225              // DW^2 displacements
#define CH   675              // PP*3 channels per control point
#define CHP  676              // padded row stride (4-elem aligned -> 8B-aligned half4)
#define CC   8                // feature channels
#define VV   64               // volume side
#define V3   262144           // 64^3

typedef __attribute__((ext_vector_type(8))) _Float16 half8;
typedef __attribute__((ext_vector_type(4))) _Float16 half4;
typedef __attribute__((ext_vector_type(2))) _Float16 half2v;

__device__ __forceinline__ float sv(int i) {
    // DR * ((2i+1)/DW - 1)
    return 0.4f * ((2.f * i + 1.f) * (1.f / 15.f) - 1.f);
}

// --- trilerp axis helpers ---
// pair axis (fast-sweep dim): clamp to [0, VV-2] pair base + edge weights
__device__ __forceinline__ void paxis(float pc, int& p0, float& wA, float& wB) {
    float iu = 0.5f * ((pc + 1.f) * (float)VV - 1.f);
    float u0f = floorf(iu);
    int u0 = (int)u0f;
    p0 = min(max(u0, 0), VV - 2);
    wA = (u0 < 0) ? 1.f : ((u0 >= VV - 1) ? 0.f : (1.f - (iu - u0f)));
    wB = 1.f - wA;
}
// standard two-point axis
__device__ __forceinline__ void vaxis(float pc, int& c0, int& c1, float& w0, float& w1) {
    float iv = 0.5f * ((pc + 1.f) * (float)VV - 1.f);
    float v0f = floorf(iv);
    float fv = iv - v0f;
    int v0 = (int)v0f;
    c0 = min(max(v0, 0), VV - 1);
    c1 = min(max(v0 + 1, 0), VV - 1);
    w0 = 1.f - fv; w1 = fv;
}

// trilerp (pair-load form) + SSD vs f8
__device__ __forceinline__ float sample_ssd(const _Float16* __restrict__ vol,
        int p0, float wAu, float wBu,
        int c0, int c1, float wv0, float wv1,
        int e0, int e1, float ww0, float ww1,
        half8 f8) {
    half8 acc = {0, 0, 0, 0, 0, 0, 0, 0};
#define PAIR(WC, VC, WGT) {                                               \
        float fA_ = (WGT) * wAu, fB_ = (WGT) * wBu;                       \
        _Float16 hA_ = (_Float16)fA_, hB_ = (_Float16)fB_;                \
        half8 hA8 = {hA_, hA_, hA_, hA_, hA_, hA_, hA_, hA_};             \
        half8 hB8 = {hB_, hB_, hB_, hB_, hB_, hB_, hB_, hB_};             \
        const _Float16* vp = vol + (size_t)((((WC) * VV) + (VC)) * VV + p0) * 8; \
        half8 lo = *(const half8*)vp;                                     \
        half8 hi = *(const half8*)(vp + 8);                               \
        acc += hA8 * lo;                                                  \
        acc += hB8 * hi;                                                  \
    }
    PAIR(e0, c0, ww0 * wv0)
    PAIR(e0, c1, ww0 * wv1)
    PAIR(e1, c0, ww1 * wv0)
    PAIR(e1, c1, ww1 * wv1)
#undef PAIR
    half8 d8 = f8 - acc;
#if __has_builtin(__builtin_amdgcn_fdot2)
    float ssd = 0.f;
#pragma unroll
    for (int j = 0; j < 4; j++) {
        half2v d2 = {d8[2 * j], d8[2 * j + 1]};
        ssd = __builtin_amdgcn_fdot2(d2, d2, ssd, false);
    }
    return ssd;
#else
    float ssd = 0.f;
#pragma unroll
    for (int c = 0; c < 8; c++) { float dc = (float)d8[c]; ssd = fmaf(dc, dc, ssd); }
    return ssd;
#endif
}

// feat50 (C,D,H,W) fp32 -> two fp16 channel-last volumes:
//   volA: (z,y,x,c)  x fastest   for k=0,1 (lane sweep = x)
//   volB: (z,x,y,c)  y fastest   for k=2   (lane sweep = y)
__global__ __launch_bounds__(256) void make_vols(const float* __restrict__ in,
                                                 _Float16* __restrict__ volA,
                                                 _Float16* __restrict__ volB) {
    int v = blockIdx.x * 256 + threadIdx.x;
    if (v >= V3) return;
    int z = v >> 12, y = (v >> 6) & 63, x = v & 63;
    half8 h;
#pragma unroll
    for (int c = 0; c < CC; c++) h[c] = (_Float16)in[c * V3 + v];
    *(half8*)(volA + (size_t)v * 8) = h;
    *(half8*)(volB + (size_t)((((z << 6) | x) << 6) | y) * 8) = h;
}

// Block per n. Sampling with shared axis setups (k0/k1 share u, k1/k2 share w),
// dot2 SSD; then 4-wide chunked separable min3x3 + avg3x3; vectorized writes.
__global__ __launch_bounds__(256) void pdd_pool_n(const float* __restrict__ f00,
                                                  const _Float16* __restrict__ volA,
                                                  const _Float16* __restrict__ volB,
                                                  const float* __restrict__ grid,
                                                  const float* __restrict__ alpha,
                                                  _Float16* __restrict__ pdd,    // (n, p*3+k) stride CHP
                                                  _Float16* __restrict__ pool) { // (n, p*3+k) stride CHP
    int n = blockIdx.x;
    int tid = threadIdx.x;
    __shared__ __align__(16) _Float16 fixh[8];
    __shared__ float rowp[CHP];
    __shared__ float smin[3 * 289];
    __shared__ float poolv[CHP];

    float gx = grid[n * 3 + 0], gy = grid[n * 3 + 1], gz = grid[n * 3 + 2];

    if (tid == 8) { rowp[675] = 0.f; poolv[675] = 0.f; }
    if (tid < 8) {
        // trilerp feat00 channel tid at grid point, padding_mode='zeros' (fp32)
        float ix = 0.5f * ((gx + 1.f) * VV - 1.f);
        float iy = 0.5f * ((gy + 1.f) * VV - 1.f);
        float iz = 0.5f * ((gz + 1.f) * VV - 1.f);
        float x0f = floorf(ix), y0f = floorf(iy), z0f = floorf(iz);
        float fx = ix - x0f, fy = iy - y0f, fz = iz - z0f;
        int x0 = (int)x0f, y0 = (int)y0f, z0 = (int)z0f;
        const float* fc = f00 + tid * V3;
        float acc = 0.f;
        for (int dz = 0; dz < 2; dz++) {
            int zi = z0 + dz; float wz = dz ? fz : 1.f - fz;
            for (int dy = 0; dy < 2; dy++) {
                int yi = y0 + dy; float wy = dy ? fy : 1.f - fy;
                for (int dx = 0; dx < 2; dx++) {
                    int xi = x0 + dx; float wx = dx ? fx : 1.f - fx;
                    if (xi >= 0 && xi < VV && yi >= 0 && yi < VV && zi >= 0 && zi < VV)
                        acc += wx * wy * wz * fc[(zi * VV + yi) * VV + xi];
                }
            }
        }
        fixh[tid] = (_Float16)acc;
    }
    __syncthreads();

    if (tid < PP) {
        int p = tid;
        int h_ = p / 15, w_ = p - 15 * h_;
        float A = sv(h_), B = sv(w_);
        half8 f8 = *(const half8*)fixh;
        float a0 = alpha[0], a1 = alpha[1];

        // shared axis setups:
        int pu01; float wAu01, wBu01; paxis(gx + B, pu01, wAu01, wBu01);   // k0,k1 u-axis (x)
        int pu2 ; float wAu2 , wBu2 ; paxis(gy + B, pu2 , wAu2 , wBu2 );   // k2 u-axis (y, volB)
        int va0, va1; float wva0, wva1; vaxis(gy + A, va0, va1, wva0, wva1); // k0 v-axis
        int wa0, wa1; float wwa0, wwa1; vaxis(gz + A, wa0, wa1, wwa0, wwa1); // k1,k2 w-axis
        int zu0, zu1; float wzu0, wzu1; vaxis(gz, zu0, zu1, wzu0, wzu1);     // k0 w-axis (uniform)
        int vy0, vy1; float wvy0, wvy1; vaxis(gy, vy0, vy1, wvy0, wvy1);     // k1 v-axis (uniform)
        int vx0, vx1; float wvx0, wvx1; vaxis(gx, vx0, vx1, wvx0, wvx1);     // k2 v-axis (uniform)

        float s0 = sample_ssd(volA, pu01, wAu01, wBu01, va0, va1, wva0, wva1, zu0, zu1, wzu0, wzu1, f8);
        float s1 = sample_ssd(volA, pu01, wAu01, wBu01, vy0, vy1, wvy0, wvy1, wa0, wa1, wwa0, wwa1, f8);
        float s2 = sample_ssd(volB, pu2 , wAu2 , wBu2 , vx0, vx1, wvx0, wvx1, wa0, wa1, wwa0, wwa1, f8);
        rowp[p * 3 + 0] = a1 + a0 * s0;
        rowp[p * 3 + 1] = a1 + a0 * s1;
        rowp[p * 3 + 2] = a1 + a0 * s2;
    }
    __syncthreads();

    // chunked separable min3x3 (pad-2 edge-clamped 15x15 -> 17x17), 4 outputs/thread.
    // 255 chunks: (k, a, bc) with bc = 4-wide output group along b.
    if (tid < 255) {
        int k = tid / 85, r = tid - 85 * k;
        int a = r / 5, bc = r - 5 * a;
        int b0 = bc * 4;
        // rows a-2, a-1, a each clamped to [0,14]  (a in 0..16)
        int ra = max(a - 2, 0) * 15;
        int rb = min(max(a - 1, 0), 14) * 15;
        int rc = min(a, 14) * 15;
        float cm[6];
#pragma unroll
        for (int j = 0; j < 6; j++) {
            int cj = min(max(b0 - 2 + j, 0), 14);
            float m0 = rowp[(ra + cj) * 3 + k];
            float m1 = rowp[(rb + cj) * 3 + k];
            float m2 = rowp[(rc + cj) * 3 + k];
            cm[j] = fminf(fminf(m0, m1), m2);
        }
#pragma unroll
        for (int o = 0; o < 4; o++) {
            int b = b0 + o;
            if (b < 17) smin[k * 289 + a * 17 + b] = fminf(fminf(cm[o], cm[o + 1]), cm[o + 2]);
        }
    }
    __syncthreads();

    // chunked separable avg3x3 over smin -> poolv, 4 outputs/thread (180 chunks)
    if (tid < 180) {
        int k = tid / 60, r = tid - 60 * k;
        int h = r >> 2, wc = r & 3;
        int w0 = wc * 4;
        const float* S = smin + k * 289;
        float cs[6];
#pragma unroll
        for (int j = 0; j < 6; j++) {
            int cj = min(w0 + j, 16);
            cs[j] = S[h * 17 + cj] + S[(h + 1) * 17 + cj] + S[(h + 2) * 17 + cj];
        }
#pragma unroll
        for (int o = 0; o < 4; o++) {
            int w = w0 + o;
            if (w < 15) poolv[(h * 15 + w) * 3 + k] = (cs[o] + cs[o + 1] + cs[o + 2]) * (1.f / 9.f);
        }
    }
    __syncthreads();

    // vectorized half4 writes of pdd (rowp) and pool (poolv)
    if (tid < 169) {
        int c0 = tid * 4;
        half4 hp, hq;
#pragma unroll
        for (int j = 0; j < 4; j++) {
            hp[j] = (_Float16)rowp[c0 + j];
            hq[j] = (_Float16)poolv[c0 + j];
        }
        *(half4*)(pdd + (size_t)n * CHP + c0) = hp;
        *(half4*)(pool + (size_t)n * CHP + c0) = hq;
    }
}

// z-axis 5-tap triangle [1,2,3,2,1]/9, edge-clamped, sliding window.
// One thread per (zy-row, half4 chunk); half4 loads: 8B/lane, coalesced.
__global__ __launch_bounds__(256) void gs_z4(const _Float16* __restrict__ in,
                                             _Float16* __restrict__ out) {
    const int COLS = GS2 * 169;            // (y,x) rows x 169 half4 chunks
    int id = blockIdx.x * 256 + threadIdx.x;
    if (id >= COLS) return;
    int row = id / 169, c4 = id - 169 * row;
    size_t base = (size_t)row * CHP + c4 * 4;
    const size_t ZS = (size_t)GS2 * CHP;
    const float w0 = 1.f / 9.f, w1 = 2.f / 9.f, w2 = 3.f / 9.f;

    half4 h0 = *(const half4*)(in + base);
    half4 h3 = *(const half4*)(in + base + ZS);
    half4 h4 = *(const half4*)(in + base + 2 * ZS);
    float v0[4], v1[4], v2[4], v3[4], v4[4];
#pragma unroll
    for (int j = 0; j < 4; j++) {
        v0[j] = (float)h0[j]; v1[j] = v0[j]; v2[j] = v0[j];
        v3[j] = (float)h3[j]; v4[j] = (float)h4[j];
    }
    for (int z = 0; z < GS; z++) {
        half4 o;
#pragma unroll
        for (int j = 0; j < 4; j++)
            o[j] = (_Float16)(w0 * (v0[j] + v4[j]) + w1 * (v1[j] + v3[j]) + w2 * v2[j]);
        *(half4*)(out + base + (size_t)z * ZS) = o;
        int zn = z + 3; if (zn > GS - 1) zn = GS - 1;
        half4 hn = *(const half4*)(in + base + (size_t)zn * ZS);
#pragma unroll
        for (int j = 0; j < 4; j++) {
            v0[j] = v1[j]; v1[j] = v2[j]; v2[j] = v3[j]; v3[j] = v4[j];
            v4[j] = (float)hn[j];
        }
    }
}

// Per n: y-axis 5-tap triangle on z-smoothed pool1 (5-row gather),
// cost = a4 + a2*pdd + a3*smooth (fp32 in LDS), chunked min3x3+avg3x3 -> pool2.
__global__ __launch_bounds__(256) void cost_pool2_y(const _Float16* __restrict__ zs,
                                                    const _Float16* __restrict__ pdd,
                                                    const float* __restrict__ alpha,
                                                    _Float16* __restrict__ pool2) {
    int n = blockIdx.x, tid = threadIdx.x;
    int x = n % GS; int zy = n / GS; int y = zy % GS; int z = zy / GS;
    __shared__ float rowp[CHP];
    __shared__ float smin[3 * 289];
    __shared__ float poolv[CHP];

    if (tid == 169) poolv[675] = 0.f;
    if (tid < 169) {
        int c0 = tid * 4;
        float s0 = 0.f, s1 = 0.f, s2 = 0.f, s3 = 0.f;
#pragma unroll
        for (int dy = 0; dy < 5; dy++) {
            int yy = min(max(y + dy - 2, 0), GS - 1);
            size_t off = ((size_t)(z * GS + yy) * GS + x) * CHP + c0;
            float w = (3.f - fabsf((float)dy - 2.f)) * (1.f / 9.f);
            half4 hv = *(const half4*)(zs + off);
            s0 = fmaf(w, (float)hv[0], s0);
            s1 = fmaf(w, (float)hv[1], s1);
            s2 = fmaf(w, (float)hv[2], s2);
            s3 = fmaf(w, (float)hv[3], s3);
        }
        float a2 = alpha[2], a3 = alpha[3], a4 = alpha[4];
        half4 pv = *(const half4*)(pdd + (size_t)n * CHP + c0);
        rowp[c0 + 0] = a4 + a2 * (float)pv[0] + a3 * s0;
        rowp[c0 + 1] = a4 + a2 * (float)pv[1] + a3 * s1;
        rowp[c0 + 2] = a4 + a2 * (float)pv[2] + a3 * s2;
        rowp[c0 + 3] = a4 + a2 * (float)pv[3] + a3 * s3;
    }
    __syncthreads();

    if (tid < 255) {
        int k = tid / 85, r = tid - 85 * k;
        int a = r / 5, bc = r - 5 * a;
        int b0 = bc * 4;
        // rows a-2, a-1, a each clamped to [0,14]  (a in 0..16)
        int ra = max(a - 2, 0) * 15;
        int rb = min(max(a - 1, 0), 14) * 15;
        int rc = min(a, 14) * 15;
        float cm[6];
#pragma unroll
        for (int j = 0; j < 6; j++) {
            int cj = min(max(b0 - 2 + j, 0), 14);
            float m0 = rowp[(ra + cj) * 3 + k];
            float m1 = rowp[(rb + cj) * 3 + k];
            float m2 = rowp[(rc + cj) * 3 + k];
            cm[j] = fminf(fminf(m0, m1), m2);
        }
#pragma unroll
        for (int o = 0; o < 4; o++) {
            int b = b0 + o;
            if (b < 17) smin[k * 289 + a * 17 + b] = fminf(fminf(cm[o], cm[o + 1]), cm[o + 2]);
        }
    }
    __syncthreads();

    if (tid < 180) {
        int k = tid / 60, r = tid - 60 * k;
        int h = r >> 2, wc = r & 3;
        int w0 = wc * 4;
        const float* S = smin + k * 289;
        float cs[6];
#pragma unroll
        for (int j = 0; j < 6; j++) {
            int cj = min(w0 + j, 16);
            cs[j] = S[h * 17 + cj] + S[(h + 1) * 17 + cj] + S[(h + 2) * 17 + cj];
        }
#pragma unroll
        for (int o = 0; o < 4; o++) {
            int w = w0 + o;
            if (w < 15) poolv[(h * 15 + w) * 3 + k] = (cs[o] + cs[o + 1] + cs[o + 2]) * (1.f / 9.f);
        }
    }
    __syncthreads();

    if (tid < 169) {
        int c0 = tid * 4;
        half4 hq;
#pragma unroll
        for (int j = 0; j < 4; j++) hq[j] = (_Float16)poolv[c0 + j];
        *(half4*)(pool2 + (size_t)n * CHP + c0) = hq;
    }
}

// Per n: y-axis 5-tap triangle on z-smoothed pool2 -> cost_avg (fp32, out2),
// then softmax over p per (n,k) + pred_xyz einsum straight from LDS.
__global__ __launch_bounds__(256) void smooth_y_softmax(const _Float16* __restrict__ zs,
                                                        const float* __restrict__ alpha,
                                                        float* __restrict__ ca,     // cost_avg (N*675 fp32)
                                                        float* __restrict__ soft,   // cost_soft (N*675 fp32)
                                                        float* __restrict__ pred) { // pred_xyz (N*3)
    int n = blockIdx.x, tid = threadIdx.x;
    int x = n % GS; int zy = n / GS; int y = zy % GS; int z = zy / GS;
    int wave = tid >> 6, lane = tid & 63;
    __shared__ float vals[CHP];
    __shared__ float partial[3][3];

    if (tid < 169) {
        int c0 = tid * 4;
        float s0 = 0.f, s1 = 0.f, s2 = 0.f, s3 = 0.f;
#pragma unroll
        for (int dy = 0; dy < 5; dy++) {
            int yy = min(max(y + dy - 2, 0), GS - 1);
            size_t off = ((size_t)(z * GS + yy) * GS + x) * CHP + c0;
            float w = (3.f - fabsf((float)dy - 2.f)) * (1.f / 9.f);
            half4 hv = *(const half4*)(zs + off);
            s0 = fmaf(w, (float)hv[0], s0);
            s1 = fmaf(w, (float)hv[1], s1);
            s2 = fmaf(w, (float)hv[2], s2);
            s3 = fmaf(w, (float)hv[3], s3);
        }
        vals[c0 + 0] = s0;
        vals[c0 + 1] = s1;
        vals[c0 + 2] = s2;
        vals[c0 + 3] = s3;
    }
    __syncthreads();

    // write cost_avg (fp32, exact 675 stride)
    for (int i = tid; i < CH; i += 256) ca[(size_t)n * CH + i] = vals[i];
    __syncthreads();

    float a5 = alpha[5];
    if (wave < 3) {
        int k = wave;
        float v[4], e[4];
        float m = -1e30f;
#pragma unroll
        for (int j = 0; j < 4; j++) {
            int p = lane + 64 * j;
            v[j] = (p < PP) ? -a5 * vals[p * 3 + k] : -1e30f;
            m = fmaxf(m, v[j]);
        }
#pragma unroll
        for (int o = 32; o > 0; o >>= 1) m = fmaxf(m, __shfl_xor(m, o));
        float sum = 0.f;
#pragma unroll
        for (int j = 0; j < 4; j++) {
            int p = lane + 64 * j;
            e[j] = (p < PP) ? __expf(v[j] - m) : 0.f;
            sum += e[j];
        }
#pragma unroll
        for (int o = 32; o > 0; o >>= 1) sum += __shfl_xor(sum, o);
        float inv = 1.f / sum;
        float px = 0.f, py = 0.f, pz = 0.f;
#pragma unroll
        for (int j = 0; j < 4; j++) {
            int p = lane + 64 * j;
            if (p < PP) {
                float s = e[j] * inv;
                vals[p * 3 + k] = s;
                int h_ = p / 15, w_ = p - 15 * h_;
                float A = sv(h_), B = sv(w_);
                if (k == 0)      { px += s * B; py += s * A; }
                else if (k == 1) { px += s * B; pz += s * A; }
                else             { py += s * B; pz += s * A; }
            }
        }
#pragma unroll
        for (int o = 32; o > 0; o >>= 1) {
            px += __shfl_xor(px, o);
            py += __shfl_xor(py, o);
            pz += __shfl_xor(pz, o);
        }
        if (lane == 0) { partial[k][0] = px; partial[k][1] = py; partial[k][2] = pz; }
    }
    __syncthreads();
    if (tid < 3) pred[(size_t)n * 3 + tid] = 0.5f * (partial[0][tid] + partial[1][tid] + partial[2][tid]);
    for (int i = tid; i < CH; i += 256) soft[(size_t)n * CH + i] = vals[i];
}

extern "C" void kernel_launch(void* const* d_in, const int* in_sizes, int n_in,
                              void* d_out, int out_size, void* d_ws, size_t ws_size,
                              hipStream_t stream) {
    const float* f00   = (const float*)d_in[0];
    const float* f50   = (const float*)d_in[1];
    // d_in[2] (shift_2d_min) broadcast of shift_2d -- unused
    const float* grid  = (const float*)d_in[3];
    // d_in[4] (shift_2d) recomputed analytically -- unused
    const float* alpha = (const float*)d_in[5];

    float* out0 = (float*)d_out;                   // cost_soft  (N*675)
    float* out1 = out0 + (size_t)NCP * CH;         // pred_xyz   (N*3)
    float* out2 = out1 + (size_t)NCP * 3;          // cost_avg   (N*675)

    char* ws = (char*)d_ws;
    _Float16* volA = (_Float16*)ws;                          // 4MB
    _Float16* volB = volA + (size_t)V3 * 8;                  // 4MB
    _Float16* H0 = volB + (size_t)V3 * 8;                    // N*CHP fp16 (pdd)
    _Float16* H1 = H0 + (size_t)NCP * CHP;                   // N*CHP fp16 (pool1 -> pool2)
    _Float16* H2 = H1 + (size_t)NCP * CHP;                   // N*CHP fp16 (z-smooth tmp)

    make_vols<<<(V3 + 255) / 256, 256, 0, stream>>>(f50, volA, volB);

    // pdd + pool1 fused, ORIGINAL (p*3+k) layout rows, contiguous fp16 writes
    pdd_pool_n<<<NCP, 256, 0, stream>>>(f00, volA, volB, grid, alpha, H0, H1);

    const int COLS = GS2 * 169;
    const int gbz = (COLS + 255) / 256;

    // smooth1 = z-pass (streaming) + y-pass fused into cost+pool2 (5-row gather)
    gs_z4<<<gbz, 256, 0, stream>>>(H1, H2);
    cost_pool2_y<<<NCP, 256, 0, stream>>>(H2, H0, alpha, H1);   // pool2 -> H1

    // smooth2 = z-pass + y-pass fused into cost_avg + softmax
    gs_z4<<<gbz, 256, 0, stream>>>(H1, H2);
    smooth_y_softmax<<<NCP, 256, 0, stream>>>(H2, alpha, out2, out0, out1);
}

// Round 6
// 484.274 us; speedup vs baseline: 1.1822x; 1.0018x over previous
//
#include <hip/hip_runtime.h>
#include <math.h>

// Problem constants
#define GS   29
#define GS2  841
#define NCP  24389            // 29^3 control points
#define DW   15
#define PP   225              // DW^2 displacements
#define CH   675              // PP*3 channels per control point
#define CHP  676              // padded row stride (4-elem aligned -> 8B-aligned half4)
#define CC   8                // feature channels
#define VV   64               // volume side
#define V3   262144           // 64^3
#define RP   237              // per-k LDS plane stride (237%32=13 -> k-planes on distinct banks)

typedef __attribute__((ext_vector_type(8))) _Float16 half8;
typedef __attribute__((ext_vector_type(4))) _Float16 half4;
typedef __attribute__((ext_vector_type(2))) _Float16 half2v;

__device__ __forceinline__ float sv(int i) {
    // DR * ((2i+1)/DW - 1)
    return 0.4f * ((2.f * i + 1.f) * (1.f / 15.f) - 1.f);
}

// --- trilerp axis helpers ---
// pair axis (fast-sweep dim): clamp to [0, VV-2] pair base + edge weights
__device__ __forceinline__ void paxis(float pc, int& p0, float& wA, float& wB) {
    float iu = 0.5f * ((pc + 1.f) * (float)VV - 1.f);
    float u0f = floorf(iu);
    int u0 = (int)u0f;
    p0 = min(max(u0, 0), VV - 2);
    wA = (u0 < 0) ? 1.f : ((u0 >= VV - 1) ? 0.f : (1.f - (iu - u0f)));
    wB = 1.f - wA;
}
// standard two-point axis
__device__ __forceinline__ void vaxis(float pc, int& c0, int& c1, float& w0, float& w1) {
    float iv = 0.5f * ((pc + 1.f) * (float)VV - 1.f);
    float v0f = floorf(iv);
    float fv = iv - v0f;
    int v0 = (int)v0f;
    c0 = min(max(v0, 0), VV - 1);
    c1 = min(max(v0 + 1, 0), VV - 1);
    w0 = 1.f - fv; w1 = fv;
}

// trilerp (pair-load form) + SSD vs f8
__device__ __forceinline__ float sample_ssd(const _Float16* __restrict__ vol,
        int p0, float wAu, float wBu,
        int c0, int c1, float wv0, float wv1,
        int e0, int e1, float ww0, float ww1,
        half8 f8) {
    half8 acc = {0, 0, 0, 0, 0, 0, 0, 0};
#define PAIR(WC, VC, WGT) {                                               \
        float fA_ = (WGT) * wAu, fB_ = (WGT) * wBu;                       \
        _Float16 hA_ = (_Float16)fA_, hB_ = (_Float16)fB_;                \
        half8 hA8 = {hA_, hA_, hA_, hA_, hA_, hA_, hA_, hA_};             \
        half8 hB8 = {hB_, hB_, hB_, hB_, hB_, hB_, hB_, hB_};             \
        const _Float16* vp = vol + (size_t)((((WC) * VV) + (VC)) * VV + p0) * 8; \
        half8 lo = *(const half8*)vp;                                     \
        half8 hi = *(const half8*)(vp + 8);                               \
        acc += hA8 * lo;                                                  \
        acc += hB8 * hi;                                                  \
    }
    PAIR(e0, c0, ww0 * wv0)
    PAIR(e0, c1, ww0 * wv1)
    PAIR(e1, c0, ww1 * wv0)
    PAIR(e1, c1, ww1 * wv1)
#undef PAIR
    half8 d8 = f8 - acc;
#if __has_builtin(__builtin_amdgcn_fdot2)
    float ssd = 0.f;
#pragma unroll
    for (int j = 0; j < 4; j++) {
        half2v d2 = {d8[2 * j], d8[2 * j + 1]};
        ssd = __builtin_amdgcn_fdot2(d2, d2, ssd, false);
    }
    return ssd;
#else
    float ssd = 0.f;
#pragma unroll
    for (int c = 0; c < 8; c++) { float dc = (float)d8[c]; ssd = fmaf(dc, dc, ssd); }
    return ssd;
#endif
}

// feat50 (C,D,H,W) fp32 -> two fp16 channel-last volumes:
//   volA: (z,y,x,c)  x fastest   for k=0,1 (lane sweep = x)
//   volB: (z,x,y,c)  y fastest   for k=2   (lane sweep = y)
__global__ __launch_bounds__(256) void make_vols(const float* __restrict__ in,
                                                 _Float16* __restrict__ volA,
                                                 _Float16* __restrict__ volB) {
    int v = blockIdx.x * 256 + threadIdx.x;
    if (v >= V3) return;
    int z = v >> 12, y = (v >> 6) & 63, x = v & 63;
    half8 h;
#pragma unroll
    for (int c = 0; c < CC; c++) h[c] = (_Float16)in[c * V3 + v];
    *(half8*)(volA + (size_t)v * 8) = h;
    *(half8*)(volB + (size_t)((((z << 6) | x) << 6) | y) * 8) = h;
}

// Block per n. Sampling with shared axis setups (k0/k1 share u, k1/k2 share w),
// dot2 SSD; planar per-k LDS (bank-conflict-free); chunked separable pooling.
__global__ __launch_bounds__(256) void pdd_pool_n(const float* __restrict__ f00,
                                                  const _Float16* __restrict__ volA,
                                                  const _Float16* __restrict__ volB,
                                                  const float* __restrict__ grid,
                                                  const float* __restrict__ alpha,
                                                  _Float16* __restrict__ pdd,    // (n, p*3+k) stride CHP
                                                  _Float16* __restrict__ pool) { // (n, p*3+k) stride CHP
    int n = blockIdx.x;
    int tid = threadIdx.x;
    __shared__ __align__(16) _Float16 fixh[8];
    __shared__ float rowp2[3][RP];     // per-k planar pdd row (p-major)
    __shared__ float smin[3 * 289];
    __shared__ float poolv2[3][RP];    // per-k planar pool row

    float gx = grid[n * 3 + 0], gy = grid[n * 3 + 1], gz = grid[n * 3 + 2];

    if (tid < 8) {
        // trilerp feat00 channel tid at grid point, padding_mode='zeros' (fp32)
        float ix = 0.5f * ((gx + 1.f) * VV - 1.f);
        float iy = 0.5f * ((gy + 1.f) * VV - 1.f);
        float iz = 0.5f * ((gz + 1.f) * VV - 1.f);
        float x0f = floorf(ix), y0f = floorf(iy), z0f = floorf(iz);
        float fx = ix - x0f, fy = iy - y0f, fz = iz - z0f;
        int x0 = (int)x0f, y0 = (int)y0f, z0 = (int)z0f;
        const float* fc = f00 + tid * V3;
        float acc = 0.f;
        for (int dz = 0; dz < 2; dz++) {
            int zi = z0 + dz; float wz = dz ? fz : 1.f - fz;
            for (int dy = 0; dy < 2; dy++) {
                int yi = y0 + dy; float wy = dy ? fy : 1.f - fy;
                for (int dx = 0; dx < 2; dx++) {
                    int xi = x0 + dx; float wx = dx ? fx : 1.f - fx;
                    if (xi >= 0 && xi < VV && yi >= 0 && yi < VV && zi >= 0 && zi < VV)
                        acc += wx * wy * wz * fc[(zi * VV + yi) * VV + xi];
                }
            }
        }
        fixh[tid] = (_Float16)acc;
    }
    // idle lanes zero the pad slots of the planar buffers (p >= 225)
    if (tid >= 225 && tid < 228) {
        int k = tid - 225;
        for (int q = PP; q < RP; q++) { rowp2[k][q] = 0.f; poolv2[k][q] = 0.f; }
    }
    __syncthreads();

    if (tid < PP) {
        int p = tid;
        int h_ = p / 15, w_ = p - 15 * h_;
        float A = sv(h_), B = sv(w_);
        half8 f8 = *(const half8*)fixh;
        float a0 = alpha[0], a1 = alpha[1];

        // shared axis setups:
        int pu01; float wAu01, wBu01; paxis(gx + B, pu01, wAu01, wBu01);   // k0,k1 u-axis (x)
        int pu2 ; float wAu2 , wBu2 ; paxis(gy + B, pu2 , wAu2 , wBu2 );   // k2 u-axis (y, volB)
        int va0, va1; float wva0, wva1; vaxis(gy + A, va0, va1, wva0, wva1); // k0 v-axis
        int wa0, wa1; float wwa0, wwa1; vaxis(gz + A, wa0, wa1, wwa0, wwa1); // k1,k2 w-axis
        int zu0, zu1; float wzu0, wzu1; vaxis(gz, zu0, zu1, wzu0, wzu1);     // k0 w-axis (uniform)
        int vy0, vy1; float wvy0, wvy1; vaxis(gy, vy0, vy1, wvy0, wvy1);     // k1 v-axis (uniform)
        int vx0, vx1; float wvx0, wvx1; vaxis(gx, vx0, vx1, wvx0, wvx1);     // k2 v-axis (uniform)

        float s0 = sample_ssd(volA, pu01, wAu01, wBu01, va0, va1, wva0, wva1, zu0, zu1, wzu0, wzu1, f8);
        float s1 = sample_ssd(volA, pu01, wAu01, wBu01, vy0, vy1, wvy0, wvy1, wa0, wa1, wwa0, wwa1, f8);
        float s2 = sample_ssd(volB, pu2 , wAu2 , wBu2 , vx0, vx1, wvx0, wvx1, wa0, wa1, wwa0, wwa1, f8);
        rowp2[0][p] = a1 + a0 * s0;
        rowp2[1][p] = a1 + a0 * s1;
        rowp2[2][p] = a1 + a0 * s2;
    }
    __syncthreads();

    // chunked separable min3x3 (pad-2 edge-clamped 15x15 -> 17x17), 4 outputs/thread.
    if (tid < 255) {
        int k = tid / 85, r = tid - 85 * k;
        int a = r / 5, bc = r - 5 * a;
        int b0 = bc * 4;
        // rows a-2, a-1, a each clamped to [0,14]  (a in 0..16)
        int ra = max(a - 2, 0) * 15;
        int rb = min(max(a - 1, 0), 14) * 15;
        int rc = min(a, 14) * 15;
        float cm[6];
#pragma unroll
        for (int j = 0; j < 6; j++) {
            int cj = min(max(b0 - 2 + j, 0), 14);
            float m0 = rowp2[k][ra + cj];
            float m1 = rowp2[k][rb + cj];
            float m2 = rowp2[k][rc + cj];
            cm[j] = fminf(fminf(m0, m1), m2);
        }
#pragma unroll
        for (int o = 0; o < 4; o++) {
            int b = b0 + o;
            if (b < 17) smin[k * 289 + a * 17 + b] = fminf(fminf(cm[o], cm[o + 1]), cm[o + 2]);
        }
    }
    __syncthreads();

    // chunked separable avg3x3 over smin -> poolv2, 4 outputs/thread (180 chunks)
    if (tid < 180) {
        int k = tid / 60, r = tid - 60 * k;
        int h = r >> 2, wc = r & 3;
        int w0 = wc * 4;
        const float* S = smin + k * 289;
        float cs[6];
#pragma unroll
        for (int j = 0; j < 6; j++) {
            int cj = min(w0 + j, 16);
            cs[j] = S[h * 17 + cj] + S[(h + 1) * 17 + cj] + S[(h + 2) * 17 + cj];
        }
#pragma unroll
        for (int o = 0; o < 4; o++) {
            int w = w0 + o;
            if (w < 15) poolv2[k][h * 15 + w] = (cs[o] + cs[o + 1] + cs[o + 2]) * (1.f / 9.f);
        }
    }
    __syncthreads();

    // vectorized half4 writes of pdd and pool in original p*3+k order
    if (tid < 169) {
        int c0 = tid * 4;
        half4 hp, hq;
#pragma unroll
        for (int j = 0; j < 4; j++) {
            int i = c0 + j;
            int p = i / 3, k = i - 3 * p;        // i=675 -> p=225 -> zeroed pad
            hp[j] = (_Float16)rowp2[k][p];
            hq[j] = (_Float16)poolv2[k][p];
        }
        *(half4*)(pdd + (size_t)n * CHP + c0) = hp;
        *(half4*)(pool + (size_t)n * CHP + c0) = hq;
    }
}

// z-axis 5-tap triangle [1,2,3,2,1]/9, edge-clamped, sliding window.
// Split into 4 z-segments (blockIdx.y) for occupancy: 557 -> 2228 blocks.
__global__ __launch_bounds__(256) void gs_z4s(const _Float16* __restrict__ in,
                                              _Float16* __restrict__ out) {
    const int COLS = GS2 * 169;            // (y,x) rows x 169 half4 chunks
    int id = blockIdx.x * 256 + threadIdx.x;
    if (id >= COLS) return;
    int seg = blockIdx.y;                  // 0..3 -> z in [8*seg, min(8*seg+8,29))
    int z0 = seg * 8;
    int z1 = min(z0 + 8, GS);
    int row = id / 169, c4 = id - 169 * row;
    size_t base = (size_t)row * CHP + c4 * 4;
    const size_t ZS = (size_t)GS2 * CHP;
    const float w0 = 1.f / 9.f, w1 = 2.f / 9.f, w2 = 3.f / 9.f;

    float v0[4], v1[4], v2[4], v3[4], v4[4];
    {
        int za = max(z0 - 2, 0), zb = max(z0 - 1, 0);
        int zd = min(z0 + 1, GS - 1), ze = min(z0 + 2, GS - 1);
        half4 ha = *(const half4*)(in + base + (size_t)za * ZS);
        half4 hb = *(const half4*)(in + base + (size_t)zb * ZS);
        half4 hc = *(const half4*)(in + base + (size_t)z0 * ZS);
        half4 hd = *(const half4*)(in + base + (size_t)zd * ZS);
        half4 he = *(const half4*)(in + base + (size_t)ze * ZS);
#pragma unroll
        for (int j = 0; j < 4; j++) {
            v0[j] = (float)ha[j]; v1[j] = (float)hb[j]; v2[j] = (float)hc[j];
            v3[j] = (float)hd[j]; v4[j] = (float)he[j];
        }
    }
    for (int z = z0; z < z1; z++) {
        half4 o;
#pragma unroll
        for (int j = 0; j < 4; j++)
            o[j] = (_Float16)(w0 * (v0[j] + v4[j]) + w1 * (v1[j] + v3[j]) + w2 * v2[j]);
        *(half4*)(out + base + (size_t)z * ZS) = o;
        int zn = min(z + 3, GS - 1);
        half4 hn = *(const half4*)(in + base + (size_t)zn * ZS);
#pragma unroll
        for (int j = 0; j < 4; j++) {
            v0[j] = v1[j]; v1[j] = v2[j]; v2[j] = v3[j]; v3[j] = v4[j];
            v4[j] = (float)hn[j];
        }
    }
}

// Per n: y-axis 5-tap triangle on z-smoothed pool1 (5-row gather),
// cost = a4 + a2*pdd + a3*smooth (planar fp32 LDS), chunked min3x3+avg3x3 -> pool2.
__global__ __launch_bounds__(256) void cost_pool2_y(const _Float16* __restrict__ zs,
                                                    const _Float16* __restrict__ pdd,
                                                    const float* __restrict__ alpha,
                                                    _Float16* __restrict__ pool2) {
    int n = blockIdx.x, tid = threadIdx.x;
    int x = n % GS; int zy = n / GS; int y = zy % GS; int z = zy / GS;
    __shared__ float rowp2[3][RP];
    __shared__ float smin[3 * 289];
    __shared__ float poolv2[3][RP];

    if (tid >= 225 && tid < 228) {
        int k = tid - 225;
        for (int q = PP; q < RP; q++) { rowp2[k][q] = 0.f; poolv2[k][q] = 0.f; }
    }
    if (tid < 169) {
        int c0 = tid * 4;
        float s0 = 0.f, s1 = 0.f, s2 = 0.f, s3 = 0.f;
#pragma unroll
        for (int dy = 0; dy < 5; dy++) {
            int yy = min(max(y + dy - 2, 0), GS - 1);
            size_t off = ((size_t)(z * GS + yy) * GS + x) * CHP + c0;
            float w = (3.f - fabsf((float)dy - 2.f)) * (1.f / 9.f);
            half4 hv = *(const half4*)(zs + off);
            s0 = fmaf(w, (float)hv[0], s0);
            s1 = fmaf(w, (float)hv[1], s1);
            s2 = fmaf(w, (float)hv[2], s2);
            s3 = fmaf(w, (float)hv[3], s3);
        }
        float a2 = alpha[2], a3 = alpha[3], a4 = alpha[4];
        half4 pv = *(const half4*)(pdd + (size_t)n * CHP + c0);
        float sm[4] = {s0, s1, s2, s3};
#pragma unroll
        for (int j = 0; j < 4; j++) {
            int i = c0 + j;
            if (i < CH) {
                int p = i / 3, k = i - 3 * p;
                rowp2[k][p] = a4 + a2 * (float)pv[j] + a3 * sm[j];
            }
        }
    }
    __syncthreads();

    if (tid < 255) {
        int k = tid / 85, r = tid - 85 * k;
        int a = r / 5, bc = r - 5 * a;
        int b0 = bc * 4;
        int ra = max(a - 2, 0) * 15;
        int rb = min(max(a - 1, 0), 14) * 15;
        int rc = min(a, 14) * 15;
        float cm[6];
#pragma unroll
        for (int j = 0; j < 6; j++) {
            int cj = min(max(b0 - 2 + j, 0), 14);
            float m0 = rowp2[k][ra + cj];
            float m1 = rowp2[k][rb + cj];
            float m2 = rowp2[k][rc + cj];
            cm[j] = fminf(fminf(m0, m1), m2);
        }
#pragma unroll
        for (int o = 0; o < 4; o++) {
            int b = b0 + o;
            if (b < 17) smin[k * 289 + a * 17 + b] = fminf(fminf(cm[o], cm[o + 1]), cm[o + 2]);
        }
    }
    __syncthreads();

    if (tid < 180) {
        int k = tid / 60, r = tid - 60 * k;
        int h = r >> 2, wc = r & 3;
        int w0 = wc * 4;
        const float* S = smin + k * 289;
        float cs[6];
#pragma unroll
        for (int j = 0; j < 6; j++) {
            int cj = min(w0 + j, 16);
            cs[j] = S[h * 17 + cj] + S[(h + 1) * 17 + cj] + S[(h + 2) * 17 + cj];
        }
#pragma unroll
        for (int o = 0; o < 4; o++) {
            int w = w0 + o;
            if (w < 15) poolv2[k][h * 15 + w] = (cs[o] + cs[o + 1] + cs[o + 2]) * (1.f / 9.f);
        }
    }
    __syncthreads();

    if (tid < 169) {
        int c0 = tid * 4;
        half4 hq;
#pragma unroll
        for (int j = 0; j < 4; j++) {
            int i = c0 + j;
            int p = i / 3, k = i - 3 * p;
            hq[j] = (_Float16)poolv2[k][p];
        }
        *(half4*)(pool2 + (size_t)n * CHP + c0) = hq;
    }
}

// Per n: y-axis 5-tap triangle on z-smoothed pool2 -> cost_avg (fp32, out2),
// then softmax over p per (n,k) + pred_xyz einsum straight from LDS.
__global__ __launch_bounds__(256) void smooth_y_softmax(const _Float16* __restrict__ zs,
                                                        const float* __restrict__ alpha,
                                                        float* __restrict__ ca,     // cost_avg (N*675 fp32)
                                                        float* __restrict__ soft,   // cost_soft (N*675 fp32)
                                                        float* __restrict__ pred) { // pred_xyz (N*3)
    int n = blockIdx.x, tid = threadIdx.x;
    int x = n % GS; int zy = n / GS; int y = zy % GS; int z = zy / GS;
    int wave = tid >> 6, lane = tid & 63;
    __shared__ float vals[CHP];
    __shared__ float partial[3][3];

    if (tid < 169) {
        int c0 = tid * 4;
        float s0 = 0.f, s1 = 0.f, s2 = 0.f, s3 = 0.f;
#pragma unroll
        for (int dy = 0; dy < 5; dy++) {
            int yy = min(max(y + dy - 2, 0), GS - 1);
            size_t off = ((size_t)(z * GS + yy) * GS + x) * CHP + c0;
            float w = (3.f - fabsf((float)dy - 2.f)) * (1.f / 9.f);
            half4 hv = *(const half4*)(zs + off);
            s0 = fmaf(w, (float)hv[0], s0);
            s1 = fmaf(w, (float)hv[1], s1);
            s2 = fmaf(w, (float)hv[2], s2);
            s3 = fmaf(w, (float)hv[3], s3);
        }
        vals[c0 + 0] = s0;
        vals[c0 + 1] = s1;
        vals[c0 + 2] = s2;
        vals[c0 + 3] = s3;
    }
    __syncthreads();

    // write cost_avg (fp32, exact 675 stride)
    for (int i = tid; i < CH; i += 256) ca[(size_t)n * CH + i] = vals[i];
    __syncthreads();

    float a5 = alpha[5];
    if (wave < 3) {
        int k = wave;
        float v[4], e[4];
        float m = -1e30f;
#pragma unroll
        for (int j = 0; j < 4; j++) {
            int p = lane + 64 * j;
            v[j] = (p < PP) ? -a5 * vals[p * 3 + k] : -1e30f;
            m = fmaxf(m, v[j]);
        }
#pragma unroll
        for (int o = 32; o > 0; o >>= 1) m = fmaxf(m, __shfl_xor(m, o));
        float sum = 0.f;
#pragma unroll
        for (int j = 0; j < 4; j++) {
            int p = lane + 64 * j;
            e[j] = (p < PP) ? __expf(v[j] - m) : 0.f;
            sum += e[j];
        }
#pragma unroll
        for (int o = 32; o > 0; o >>= 1) sum += __shfl_xor(sum, o);
        float inv = 1.f / sum;
        float px = 0.f, py = 0.f, pz = 0.f;
#pragma unroll
        for (int j = 0; j < 4; j++) {
            int p = lane + 64 * j;
            if (p < PP) {
                float s = e[j] * inv;
                vals[p * 3 + k] = s;
                int h_ = p / 15, w_ = p - 15 * h_;
                float A = sv(h_), B = sv(w_);
                if (k == 0)      { px += s * B; py += s * A; }
                else if (k == 1) { px += s * B; pz += s * A; }
                else             { py += s * B; pz += s * A; }
            }
        }
#pragma unroll
        for (int o = 32; o > 0; o >>= 1) {
            px += __shfl_xor(px, o);
            py += __shfl_xor(py, o);
            pz += __shfl_xor(pz, o);
        }
        if (lane == 0) { partial[k][0] = px; partial[k][1] = py; partial[k][2] = pz; }
    }
    __syncthreads();
    if (tid < 3) pred[(size_t)n * 3 + tid] = 0.5f * (partial[0][tid] + partial[1][tid] + partial[2][tid]);
    for (int i = tid; i < CH; i += 256) soft[(size_t)n * CH + i] = vals[i];
}

extern "C" void kernel_launch(void* const* d_in, const int* in_sizes, int n_in,
                              void* d_out, int out_size, void* d_ws, size_t ws_size,
                              hipStream_t stream) {
    const float* f00   = (const float*)d_in[0];
    const float* f50   = (const float*)d_in[1];
    // d_in[2] (shift_2d_min) broadcast of shift_2d -- unused
    const float* grid  = (const float*)d_in[3];
    // d_in[4] (shift_2d) recomputed analytically -- unused
    const float* alpha = (const float*)d_in[5];

    float* out0 = (float*)d_out;                   // cost_soft  (N*675)
    float* out1 = out0 + (size_t)NCP * CH;         // pred_xyz   (N*3)
    float* out2 = out1 + (size_t)NCP * 3;          // cost_avg   (N*675)

    char* ws = (char*)d_ws;
    _Float16* volA = (_Float16*)ws;                          // 4MB
    _Float16* volB = volA + (size_t)V3 * 8;                  // 4MB
    _Float16* H0 = volB + (size_t)V3 * 8;                    // N*CHP fp16 (pdd)
    _Float16* H1 = H0 + (size_t)NCP * CHP;                   // N*CHP fp16 (pool1 -> pool2)
    _Float16* H2 = H1 + (size_t)NCP * CHP;                   // N*CHP fp16 (z-smooth tmp)

    make_vols<<<(V3 + 255) / 256, 256, 0, stream>>>(f50, volA, volB);

    // pdd + pool1 fused, ORIGINAL (p*3+k) layout rows, contiguous fp16 writes
    pdd_pool_n<<<NCP, 256, 0, stream>>>(f00, volA, volB, grid, alpha, H0, H1);

    const int COLS = GS2 * 169;
    const int gbz = (COLS + 255) / 256;
    dim3 gz(gbz, 4);

    // smooth1 = z-pass (segmented, occupancy x4) + y-pass fused into cost+pool2
    gs_z4s<<<gz, 256, 0, stream>>>(H1, H2);
    cost_pool2_y<<<NCP, 256, 0, stream>>>(H2, H0, alpha, H1);   // pool2 -> H1

    // smooth2 = z-pass + y-pass fused into cost_avg + softmax
    gs_z4s<<<gz, 256, 0, stream>>>(H1, H2);
    smooth_y_softmax<<<NCP, 256, 0, stream>>>(H2, alpha, out2, out0, out1);
}